// Round 1
// baseline (1890.515 us; speedup 1.0000x reference)
//
#include <hip/hip_runtime.h>
#include <math.h>

// Problem constants (from reference): B=4, N=50000, E=800000, D=64
#define NB 4
#define NN 50000
#define NE 800000
#define ND 64

static const long TOT = (long)NB * NN * ND; // 12,800,000 elements per (B,N,D) tensor

// ---- degree count: deg[col[e]] += 1 ----------------------------------------
__global__ __launch_bounds__(256) void deg_kernel(const int* __restrict__ col,
                                                  float* __restrict__ deg) {
    int e = blockIdx.x * blockDim.x + threadIdx.x;
    if (e < NE) atomicAdd(&deg[col[e]], 1.0f);
}

// ---- dis[n] = rsqrt(deg[n] + 1)  (self-loop guarantees deg >= 1) -----------
__global__ __launch_bounds__(256) void dis_kernel(float* __restrict__ deg) {
    int n = blockIdx.x * blockDim.x + threadIdx.x;
    if (n < NN) deg[n] = rsqrtf(deg[n] + 1.0f);
}

// ---- norm[e] = dis[row[e]] * dis[col[e]] -----------------------------------
__global__ __launch_bounds__(256) void norm_kernel(const int* __restrict__ row,
                                                   const int* __restrict__ col,
                                                   const float* __restrict__ dis,
                                                   float* __restrict__ norm) {
    int e = blockIdx.x * blockDim.x + threadIdx.x;
    if (e < NE) norm[e] = dis[row[e]] * dis[col[e]];
}

// ---- xw[r,:] = x[r,:] @ W  (R = B*N rows, D=64) ----------------------------
// 4 waves per block; W staged in LDS; row value broadcast via shfl.
__global__ __launch_bounds__(256) void gemm_kernel(const float* __restrict__ x,
                                                   const float* __restrict__ W,
                                                   float* __restrict__ xw) {
    __shared__ float Ws[64][64]; // 16 KB
    for (int i = threadIdx.x; i < 64 * 64; i += 256) Ws[i >> 6][i & 63] = W[i];
    __syncthreads();

    const int lane = threadIdx.x & 63;
    const int waveInBlock = threadIdx.x >> 6; // 0..3
    const int ROWS_PER_BLOCK = 16;
    long base = (long)blockIdx.x * ROWS_PER_BLOCK;
    const long R = (long)NB * NN;

    for (int rr = waveInBlock; rr < ROWS_PER_BLOCK; rr += 4) {
        long r = base + rr;
        if (r >= R) return;
        float xv = x[r * ND + lane];   // coalesced: one element per lane
        float acc = 0.0f;
#pragma unroll
        for (int k = 0; k < 64; ++k) {
            acc = fmaf(__shfl(xv, k), Ws[k][lane], acc);
        }
        xw[r * ND + lane] = acc;
    }
}

// ---- agg = xw * dis[n]^2  (self-loop contribution; full overwrite) ---------
__global__ __launch_bounds__(256) void selfloop_kernel(const float* __restrict__ xw,
                                                       const float* __restrict__ dis,
                                                       float* __restrict__ agg) {
    long i = (long)blockIdx.x * blockDim.x + threadIdx.x;
    if (i < (long)NB * NN * ND) {
        int n = (int)((i >> 6) % NN);
        float dn = dis[n];
        agg[i] = xw[i] * dn * dn;
    }
}

// ---- edge scatter: agg[b,col,:] += xw[b,row,:] * norm[e] -------------------
// One wave per edge (lane = feature d), loop over batches.
__global__ __launch_bounds__(256) void scatter_kernel(const int* __restrict__ row,
                                                      const int* __restrict__ col,
                                                      const float* __restrict__ norm,
                                                      const float* __restrict__ xw,
                                                      float* __restrict__ agg) {
    long idx = (long)blockIdx.x * blockDim.x + threadIdx.x;
    int e = (int)(idx >> 6);
    int lane = (int)(idx & 63);
    if (e >= NE) return;
    int r = row[e];
    int c = col[e];
    float nv = norm[e];
#pragma unroll
    for (int b = 0; b < NB; ++b) {
        float v = xw[(long)b * NN * ND + (long)r * ND + lane] * nv;
        atomicAdd(&agg[(long)b * NN * ND + (long)c * ND + lane], v);
    }
}

// ---- out = tanh(agg + bias) ------------------------------------------------
__global__ __launch_bounds__(256) void tanh_bias_kernel(const float* __restrict__ agg,
                                                        const float* __restrict__ bias,
                                                        float* __restrict__ out) {
    long i = (long)blockIdx.x * blockDim.x + threadIdx.x;
    if (i < (long)NB * NN * ND) {
        int d = (int)(i & 63);
        out[i] = tanhf(agg[i] + bias[d]);
    }
}

extern "C" void kernel_launch(void* const* d_in, const int* in_sizes, int n_in,
                              void* d_out, int out_size, void* d_ws, size_t ws_size,
                              hipStream_t stream) {
    // inputs: 0=t, 1=h, 2=edge_index, 3=W1, 4=b1, 5=W2, 6=b2
    const float* h   = (const float*)d_in[1];
    const int*   ei  = (const int*)d_in[2];
    const float* W1  = (const float*)d_in[3];
    const float* b1  = (const float*)d_in[4];
    const float* W2  = (const float*)d_in[5];
    const float* b2  = (const float*)d_in[6];
    float* out = (float*)d_out;

    const int* rowp = ei;        // edge_index[0] = sources
    const int* colp = ei + NE;   // edge_index[1] = targets

    // workspace layout (floats): xw | agg | dis | norm
    float* ws  = (float*)d_ws;
    float* xw  = ws;
    float* agg = xw + TOT;
    float* dis = agg + TOT;
    float* nrm = dis + NN;

    const int THREADS = 256;
    const int gridE   = (NE + THREADS - 1) / THREADS;      // per-edge kernels
    const int gridN   = (NN + THREADS - 1) / THREADS;
    const int gridTot = (int)((TOT + THREADS - 1) / THREADS);
    const int gridScat = (int)(((long)NE * ND + THREADS - 1) / THREADS); // wave per edge
    const int gridGemm = (int)(((long)NB * NN + 15) / 16);

    // normalization
    hipMemsetAsync(dis, 0, NN * sizeof(float), stream);
    deg_kernel<<<gridE, THREADS, 0, stream>>>(colp, dis);
    dis_kernel<<<gridN, THREADS, 0, stream>>>(dis);
    norm_kernel<<<gridE, THREADS, 0, stream>>>(rowp, colp, dis, nrm);

    // ---- layer 1: h -> out (d_out used as intermediate) ----
    gemm_kernel<<<gridGemm, THREADS, 0, stream>>>(h, W1, xw);
    selfloop_kernel<<<gridTot, THREADS, 0, stream>>>(xw, dis, agg);
    scatter_kernel<<<gridScat, THREADS, 0, stream>>>(rowp, colp, nrm, xw, agg);
    tanh_bias_kernel<<<gridTot, THREADS, 0, stream>>>(agg, b1, out);

    // ---- layer 2: out -> out ----
    gemm_kernel<<<gridGemm, THREADS, 0, stream>>>(out, W2, xw);
    selfloop_kernel<<<gridTot, THREADS, 0, stream>>>(xw, dis, agg);
    scatter_kernel<<<gridScat, THREADS, 0, stream>>>(rowp, colp, nrm, xw, agg);
    tanh_bias_kernel<<<gridTot, THREADS, 0, stream>>>(agg, b2, out);
}

// Round 2
// 911.455 us; speedup vs baseline: 2.0742x; 2.0742x over previous
//
#include <hip/hip_runtime.h>
#include <math.h>

// Problem constants (from reference): B=4, N=50000, E=800000, D=64
#define NB 4
#define NN 50000
#define NE 800000
#define ND 64

static const long TOT = (long)NB * NN * ND; // 12,800,000 floats per (B,N,D) tensor

// ---- count in-degree (targets): cnt[col[e]] += 1 ---------------------------
__global__ __launch_bounds__(256) void count_kernel(const int* __restrict__ col,
                                                    int* __restrict__ cnt) {
    int e = blockIdx.x * blockDim.x + threadIdx.x;
    if (e < NE) atomicAdd(&cnt[col[e]], 1);
}

// ---- dis[n] = rsqrt(cnt[n] + 1)  (+1 = self-loop) --------------------------
__global__ __launch_bounds__(256) void dis_kernel(const int* __restrict__ cnt,
                                                  float* __restrict__ dis) {
    int n = blockIdx.x * blockDim.x + threadIdx.x;
    if (n < NN) dis[n] = rsqrtf((float)cnt[n] + 1.0f);
}

// ---- single-block exclusive scan of cnt[NN] -> ptr[NN+1], copy -> fill -----
__global__ __launch_bounds__(256) void scan_kernel(const int* __restrict__ cnt,
                                                   int* __restrict__ ptr,
                                                   int* __restrict__ fill) {
    __shared__ int sums[256];
    const int t = threadIdx.x;
    const int CHUNK = (NN + 255) / 256; // 196
    int lo = t * CHUNK;
    int hi = min(lo + CHUNK, NN);
    int s = 0;
    for (int i = lo; i < hi; ++i) s += cnt[i];
    sums[t] = s;
    __syncthreads();
    if (t == 0) {
        int run = 0;
        for (int i = 0; i < 256; ++i) { int v = sums[i]; sums[i] = run; run += v; }
        ptr[NN] = run; // == NE
    }
    __syncthreads();
    int run = sums[t];
    for (int i = lo; i < hi; ++i) { ptr[i] = run; fill[i] = run; run += cnt[i]; }
}

// ---- CSR fill: bucket edges by target; precompute per-edge norm ------------
__global__ __launch_bounds__(256) void fill_kernel(const int* __restrict__ row,
                                                   const int* __restrict__ col,
                                                   const float* __restrict__ dis,
                                                   int* __restrict__ fill,
                                                   int* __restrict__ srow,
                                                   float* __restrict__ snorm) {
    int e = blockIdx.x * blockDim.x + threadIdx.x;
    if (e >= NE) return;
    int r = row[e], c = col[e];
    int p = atomicAdd(&fill[c], 1);
    srow[p] = r;
    snorm[p] = dis[r] * dis[c];
}

// ---- xw[n,b,:] = x[b,n,:] @ W  (interleaved output layout (N,B,D)) ---------
__global__ __launch_bounds__(256) void gemm_kernel(const float* __restrict__ x,
                                                   const float* __restrict__ W,
                                                   float* __restrict__ xw) {
    __shared__ float Ws[64][64]; // 16 KB
    for (int i = threadIdx.x; i < 64 * 64; i += 256) Ws[i >> 6][i & 63] = W[i];
    __syncthreads();

    const int lane = threadIdx.x & 63;
    const int waveInBlock = threadIdx.x >> 6; // 0..3
    const int ROWS_PER_BLOCK = 16;
    long base = (long)blockIdx.x * ROWS_PER_BLOCK;
    const long R = (long)NB * NN;

    for (int rr = waveInBlock; rr < ROWS_PER_BLOCK; rr += 4) {
        long r = base + rr;
        if (r >= R) return;
        float xv = x[r * ND + lane];   // coalesced
        float acc = 0.0f;
#pragma unroll
        for (int k = 0; k < 64; ++k) {
            acc = fmaf(__shfl(xv, k), Ws[k][lane], acc);
        }
        int b = (int)(r / NN);
        int n = (int)(r - (long)b * NN);
        xw[((long)n * NB + b) * ND + lane] = acc; // (N,B,D): 1KB/node contiguous
    }
}

// ---- fused gather + self-loop + bias + tanh --------------------------------
// One wave per target node. lane owns (b = lane>>4, d0 = (lane&15)*4) float4.
__global__ __launch_bounds__(256) void gather_kernel(const int* __restrict__ ptr,
                                                     const int* __restrict__ srow,
                                                     const float* __restrict__ snorm,
                                                     const float* __restrict__ dis,
                                                     const float* __restrict__ xw,
                                                     const float* __restrict__ bias,
                                                     float* __restrict__ out) {
    int node = blockIdx.x * 4 + (threadIdx.x >> 6);
    if (node >= NN) return;
    const int lane = threadIdx.x & 63;
    const int b = lane >> 4;
    const int d0 = (lane & 15) * 4;

    // self-loop: xw[node,:,:] * dis[node]^2
    float dn = dis[node];
    float4 acc = *(const float4*)(xw + (long)node * (NB * ND) + lane * 4);
    float sl = dn * dn;
    acc.x *= sl; acc.y *= sl; acc.z *= sl; acc.w *= sl;

    int e = ptr[node];
    const int eend = ptr[node + 1];
    for (; e + 1 < eend; e += 2) {
        int r0 = srow[e], r1 = srow[e + 1];
        float n0 = snorm[e], n1 = snorm[e + 1];
        float4 v0 = *(const float4*)(xw + (long)r0 * (NB * ND) + lane * 4);
        float4 v1 = *(const float4*)(xw + (long)r1 * (NB * ND) + lane * 4);
        acc.x = fmaf(v0.x, n0, acc.x); acc.y = fmaf(v0.y, n0, acc.y);
        acc.z = fmaf(v0.z, n0, acc.z); acc.w = fmaf(v0.w, n0, acc.w);
        acc.x = fmaf(v1.x, n1, acc.x); acc.y = fmaf(v1.y, n1, acc.y);
        acc.z = fmaf(v1.z, n1, acc.z); acc.w = fmaf(v1.w, n1, acc.w);
    }
    if (e < eend) {
        int r0 = srow[e];
        float n0 = snorm[e];
        float4 v0 = *(const float4*)(xw + (long)r0 * (NB * ND) + lane * 4);
        acc.x = fmaf(v0.x, n0, acc.x); acc.y = fmaf(v0.y, n0, acc.y);
        acc.z = fmaf(v0.z, n0, acc.z); acc.w = fmaf(v0.w, n0, acc.w);
    }

    // bias + tanh, write to (B,N,D)
    acc.x = tanhf(acc.x + bias[d0 + 0]);
    acc.y = tanhf(acc.y + bias[d0 + 1]);
    acc.z = tanhf(acc.z + bias[d0 + 2]);
    acc.w = tanhf(acc.w + bias[d0 + 3]);
    *(float4*)(out + (long)b * NN * ND + (long)node * ND + d0) = acc;
}

extern "C" void kernel_launch(void* const* d_in, const int* in_sizes, int n_in,
                              void* d_out, int out_size, void* d_ws, size_t ws_size,
                              hipStream_t stream) {
    // inputs: 0=t, 1=h, 2=edge_index, 3=W1, 4=b1, 5=W2, 6=b2
    const float* h  = (const float*)d_in[1];
    const int*   ei = (const int*)d_in[2];
    const float* W1 = (const float*)d_in[3];
    const float* b1 = (const float*)d_in[4];
    const float* W2 = (const float*)d_in[5];
    const float* b2 = (const float*)d_in[6];
    float* out = (float*)d_out;

    const int* rowp = ei;        // edge_index[0] = sources
    const int* colp = ei + NE;   // edge_index[1] = targets

    // workspace layout
    float* xw   = (float*)d_ws;                 // TOT floats (N,B,D)
    float* dis  = xw + TOT;                     // NN
    float* snorm= dis + NN;                     // NE
    int*   cnt  = (int*)(snorm + NE);           // NN
    int*   ptr  = cnt + NN;                     // NN+1
    int*   fill = ptr + NN + 1;                 // NN
    int*   srow = fill + NN;                    // NE

    const int THREADS = 256;
    const int gridE = (NE + THREADS - 1) / THREADS;
    const int gridN = (NN + THREADS - 1) / THREADS;
    const int gridGemm   = (int)(((long)NB * NN + 15) / 16);
    const int gridGather = (NN + 3) / 4; // 4 waves (nodes) per block

    // ---- normalization + CSR build ----
    hipMemsetAsync(cnt, 0, NN * sizeof(int), stream);
    count_kernel<<<gridE, THREADS, 0, stream>>>(colp, cnt);
    dis_kernel<<<gridN, THREADS, 0, stream>>>(cnt, dis);
    scan_kernel<<<1, THREADS, 0, stream>>>(cnt, ptr, fill);
    fill_kernel<<<gridE, THREADS, 0, stream>>>(rowp, colp, dis, fill, srow, snorm);

    // ---- layer 1: h -> out ----
    gemm_kernel<<<gridGemm, THREADS, 0, stream>>>(h, W1, xw);
    gather_kernel<<<gridGather, THREADS, 0, stream>>>(ptr, srow, snorm, dis, xw, b1, out);

    // ---- layer 2: out -> out ----
    gemm_kernel<<<gridGemm, THREADS, 0, stream>>>(out, W2, xw);
    gather_kernel<<<gridGather, THREADS, 0, stream>>>(ptr, srow, snorm, dis, xw, b2, out);
}

// Round 3
// 592.835 us; speedup vs baseline: 3.1889x; 1.5375x over previous
//
#include <hip/hip_runtime.h>
#include <math.h>

// Problem constants (from reference): B=4, N=50000, E=800000, D=64
#define NB 4
#define NN 50000
#define NE 800000
#define ND 64

static const long TOT = (long)NB * NN * ND; // 12,800,000 floats per (B,N,D) tensor

// ---- count in-degree (targets): cnt[col[e]] += 1 ---------------------------
__global__ __launch_bounds__(256) void count_kernel(const int* __restrict__ col,
                                                    int* __restrict__ cnt) {
    int e = blockIdx.x * blockDim.x + threadIdx.x;
    if (e < NE) atomicAdd(&cnt[col[e]], 1);
}

// ---- dis[n] = rsqrt(cnt[n] + 1)  (+1 = self-loop) --------------------------
__global__ __launch_bounds__(256) void dis_kernel(const int* __restrict__ cnt,
                                                  float* __restrict__ dis) {
    int n = blockIdx.x * blockDim.x + threadIdx.x;
    if (n < NN) dis[n] = rsqrtf((float)cnt[n] + 1.0f);
}

// ---- 1024-thread exclusive scan of cnt[NN] -> ptr[NN+1], copy -> fill ------
__global__ __launch_bounds__(1024) void scan_kernel(const int* __restrict__ cnt,
                                                    int* __restrict__ ptr,
                                                    int* __restrict__ fill) {
    __shared__ int sums[1024];
    const int t = threadIdx.x;
    const int CHUNK = (NN + 1023) / 1024; // 49
    int lo = t * CHUNK;
    int hi = min(lo + CHUNK, NN);
    int s = 0;
    for (int i = lo; i < hi; ++i) s += cnt[i];
    sums[t] = s;
    __syncthreads();
    // Hillis-Steele inclusive scan over 1024 partials
    for (int off = 1; off < 1024; off <<= 1) {
        int v = (t >= off) ? sums[t - off] : 0;
        __syncthreads();
        sums[t] += v;
        __syncthreads();
    }
    int run = (t == 0) ? 0 : sums[t - 1];
    if (t == 1023) ptr[NN] = sums[1023]; // == NE
    for (int i = lo; i < hi; ++i) { ptr[i] = run; fill[i] = run; run += cnt[i]; }
}

// ---- CSR fill: bucket edges by target; precompute per-edge norm ------------
__global__ __launch_bounds__(256) void fill_kernel(const int* __restrict__ row,
                                                   const int* __restrict__ col,
                                                   const float* __restrict__ dis,
                                                   int* __restrict__ fill,
                                                   int* __restrict__ srow,
                                                   float* __restrict__ snorm) {
    int e = blockIdx.x * blockDim.x + threadIdx.x;
    if (e >= NE) return;
    int r = row[e], c = col[e];
    int p = atomicAdd(&fill[c], 1);
    srow[p] = r;
    snorm[p] = dis[r] * dis[c];
}

// ---- tiled GEMM: xw[n,b,:] = x[b,n,:] @ W   (output layout (N,B,D)) --------
// 64x64 output tile per block; 256 threads x (4 rows x 4 cols) register block.
__global__ __launch_bounds__(256) void gemm_kernel(const float* __restrict__ x,
                                                   const float* __restrict__ W,
                                                   float* __restrict__ xw) {
    __shared__ float Xs[64][65]; // padded: conflict-free column reads
    __shared__ float Ws[64][64]; // Ws[k][c]
    const int tid = threadIdx.x;
    const long row0 = (long)blockIdx.x * 64;

    for (int i = tid; i < 4096; i += 256) Ws[i >> 6][i & 63] = W[i];
    for (int i = tid; i < 4096; i += 256) {
        int r = i >> 6, k = i & 63;
        Xs[r][k] = x[(row0 + r) * ND + k];
    }
    __syncthreads();

    const int tc = tid & 15, tr = tid >> 4;
    const int c0 = tc * 4, r0 = tr * 4;
    float4 a0 = {0,0,0,0}, a1 = {0,0,0,0}, a2 = {0,0,0,0}, a3 = {0,0,0,0};

#pragma unroll
    for (int k = 0; k < 64; ++k) {
        float4 w = *(const float4*)&Ws[k][c0];
        float x0 = Xs[r0 + 0][k];
        float x1 = Xs[r0 + 1][k];
        float x2 = Xs[r0 + 2][k];
        float x3 = Xs[r0 + 3][k];
        a0.x = fmaf(x0, w.x, a0.x); a0.y = fmaf(x0, w.y, a0.y);
        a0.z = fmaf(x0, w.z, a0.z); a0.w = fmaf(x0, w.w, a0.w);
        a1.x = fmaf(x1, w.x, a1.x); a1.y = fmaf(x1, w.y, a1.y);
        a1.z = fmaf(x1, w.z, a1.z); a1.w = fmaf(x1, w.w, a1.w);
        a2.x = fmaf(x2, w.x, a2.x); a2.y = fmaf(x2, w.y, a2.y);
        a2.z = fmaf(x2, w.z, a2.z); a2.w = fmaf(x2, w.w, a2.w);
        a3.x = fmaf(x3, w.x, a3.x); a3.y = fmaf(x3, w.y, a3.y);
        a3.z = fmaf(x3, w.z, a3.z); a3.w = fmaf(x3, w.w, a3.w);
    }

    float4 accs[4] = {a0, a1, a2, a3};
#pragma unroll
    for (int j = 0; j < 4; ++j) {
        long r = row0 + r0 + j;
        int b = (int)(r / NN);
        int n = (int)(r - (long)b * NN);
        *(float4*)&xw[((long)n * NB + b) * ND + c0] = accs[j]; // (N,B,D)
    }
}

// ---- fused gather + self-loop + bias + tanh --------------------------------
// One wave per target node. lane owns (b = lane>>4, d0 = (lane&15)*4) float4.
__global__ __launch_bounds__(256) void gather_kernel(const int* __restrict__ ptr,
                                                     const int* __restrict__ srow,
                                                     const float* __restrict__ snorm,
                                                     const float* __restrict__ dis,
                                                     const float* __restrict__ xw,
                                                     const float* __restrict__ bias,
                                                     float* __restrict__ out) {
    int node = blockIdx.x * 4 + (threadIdx.x >> 6);
    if (node >= NN) return;
    const int lane = threadIdx.x & 63;
    const int b = lane >> 4;
    const int d0 = (lane & 15) * 4;

    // self-loop: xw[node,:,:] * dis[node]^2
    float dn = dis[node];
    float4 acc = *(const float4*)(xw + (long)node * (NB * ND) + lane * 4);
    float sl = dn * dn;
    acc.x *= sl; acc.y *= sl; acc.z *= sl; acc.w *= sl;

    int e = ptr[node];
    const int eend = ptr[node + 1];
    for (; e + 3 < eend; e += 4) {
        int r0 = srow[e], r1 = srow[e + 1], r2 = srow[e + 2], r3 = srow[e + 3];
        float n0 = snorm[e], n1 = snorm[e + 1], n2 = snorm[e + 2], n3 = snorm[e + 3];
        float4 v0 = *(const float4*)(xw + (long)r0 * (NB * ND) + lane * 4);
        float4 v1 = *(const float4*)(xw + (long)r1 * (NB * ND) + lane * 4);
        float4 v2 = *(const float4*)(xw + (long)r2 * (NB * ND) + lane * 4);
        float4 v3 = *(const float4*)(xw + (long)r3 * (NB * ND) + lane * 4);
        acc.x = fmaf(v0.x, n0, acc.x); acc.y = fmaf(v0.y, n0, acc.y);
        acc.z = fmaf(v0.z, n0, acc.z); acc.w = fmaf(v0.w, n0, acc.w);
        acc.x = fmaf(v1.x, n1, acc.x); acc.y = fmaf(v1.y, n1, acc.y);
        acc.z = fmaf(v1.z, n1, acc.z); acc.w = fmaf(v1.w, n1, acc.w);
        acc.x = fmaf(v2.x, n2, acc.x); acc.y = fmaf(v2.y, n2, acc.y);
        acc.z = fmaf(v2.z, n2, acc.z); acc.w = fmaf(v2.w, n2, acc.w);
        acc.x = fmaf(v3.x, n3, acc.x); acc.y = fmaf(v3.y, n3, acc.y);
        acc.z = fmaf(v3.z, n3, acc.z); acc.w = fmaf(v3.w, n3, acc.w);
    }
    for (; e < eend; ++e) {
        int r0 = srow[e];
        float n0 = snorm[e];
        float4 v0 = *(const float4*)(xw + (long)r0 * (NB * ND) + lane * 4);
        acc.x = fmaf(v0.x, n0, acc.x); acc.y = fmaf(v0.y, n0, acc.y);
        acc.z = fmaf(v0.z, n0, acc.z); acc.w = fmaf(v0.w, n0, acc.w);
    }

    // bias + tanh, write to (B,N,D)
    acc.x = tanhf(acc.x + bias[d0 + 0]);
    acc.y = tanhf(acc.y + bias[d0 + 1]);
    acc.z = tanhf(acc.z + bias[d0 + 2]);
    acc.w = tanhf(acc.w + bias[d0 + 3]);
    *(float4*)(out + (long)b * NN * ND + (long)node * ND + d0) = acc;
}

extern "C" void kernel_launch(void* const* d_in, const int* in_sizes, int n_in,
                              void* d_out, int out_size, void* d_ws, size_t ws_size,
                              hipStream_t stream) {
    // inputs: 0=t, 1=h, 2=edge_index, 3=W1, 4=b1, 5=W2, 6=b2
    const float* h  = (const float*)d_in[1];
    const int*   ei = (const int*)d_in[2];
    const float* W1 = (const float*)d_in[3];
    const float* b1 = (const float*)d_in[4];
    const float* W2 = (const float*)d_in[5];
    const float* b2 = (const float*)d_in[6];
    float* out = (float*)d_out;

    const int* rowp = ei;        // edge_index[0] = sources
    const int* colp = ei + NE;   // edge_index[1] = targets

    // workspace layout
    float* xw   = (float*)d_ws;                 // TOT floats, (N,B,D)
    float* dis  = xw + TOT;                     // NN
    float* snorm= dis + NN;                     // NE
    int*   cnt  = (int*)(snorm + NE);           // NN
    int*   ptr  = cnt + NN;                     // NN+1
    int*   fill = ptr + NN + 1;                 // NN
    int*   srow = fill + NN;                    // NE

    const int THREADS = 256;
    const int gridE = (NE + THREADS - 1) / THREADS;
    const int gridN = (NN + THREADS - 1) / THREADS;
    const int gridGemm   = (int)(((long)NB * NN) / 64); // 3125, R divisible by 64
    const int gridGather = (NN + 3) / 4;

    // ---- normalization + CSR build ----
    hipMemsetAsync(cnt, 0, NN * sizeof(int), stream);
    count_kernel<<<gridE, THREADS, 0, stream>>>(colp, cnt);
    dis_kernel<<<gridN, THREADS, 0, stream>>>(cnt, dis);
    scan_kernel<<<1, 1024, 0, stream>>>(cnt, ptr, fill);
    fill_kernel<<<gridE, THREADS, 0, stream>>>(rowp, colp, dis, fill, srow, snorm);

    // ---- layer 1: h -> out ----
    gemm_kernel<<<gridGemm, THREADS, 0, stream>>>(h, W1, xw);
    gather_kernel<<<gridGather, THREADS, 0, stream>>>(ptr, srow, snorm, dis, xw, b1, out);

    // ---- layer 2: out -> out ----
    gemm_kernel<<<gridGemm, THREADS, 0, stream>>>(out, W2, xw);
    gather_kernel<<<gridGather, THREADS, 0, stream>>>(ptr, srow, snorm, dis, xw, b2, out);
}

// Round 4
// 559.948 us; speedup vs baseline: 3.3762x; 1.0587x over previous
//
#include <hip/hip_runtime.h>
#include <math.h>

// Problem constants (from reference): B=4, N=50000, E=800000, D=64
#define NB 4
#define NN 50000
#define NE 800000
#define ND 64

static const long TOT = (long)NB * NN * ND; // 12,800,000 elements per (B,N,D) tensor

typedef unsigned int uint_t;

// f32 -> bf16 (round-to-nearest-even)
__device__ __forceinline__ unsigned short f2b(float f) {
    unsigned x = __float_as_uint(f);
    unsigned r = (x + 0x7fffu + ((x >> 16) & 1u)) >> 16;
    return (unsigned short)r;
}
// bf16 (as ushort) -> f32: exact, just shift
__device__ __forceinline__ float b2f(unsigned short u) {
    return __uint_as_float(((unsigned)u) << 16);
}
__device__ __forceinline__ float4 b2f4(ushort4 u) {
    float4 f;
    f.x = b2f(u.x); f.y = b2f(u.y); f.z = b2f(u.z); f.w = b2f(u.w);
    return f;
}

// ---- count in-degree (targets): cnt[col[e]] += 1 ---------------------------
__global__ __launch_bounds__(256) void count_kernel(const int* __restrict__ col,
                                                    int* __restrict__ cnt) {
    int e = blockIdx.x * blockDim.x + threadIdx.x;
    if (e < NE) atomicAdd(&cnt[col[e]], 1);
}

// ---- dis[n] = rsqrt(cnt[n] + 1)  (+1 = self-loop) --------------------------
__global__ __launch_bounds__(256) void dis_kernel(const int* __restrict__ cnt,
                                                  float* __restrict__ dis) {
    int n = blockIdx.x * blockDim.x + threadIdx.x;
    if (n < NN) dis[n] = rsqrtf((float)cnt[n] + 1.0f);
}

// ---- 1024-thread exclusive scan of cnt[NN] -> ptr[NN+1], copy -> fill ------
__global__ __launch_bounds__(1024) void scan_kernel(const int* __restrict__ cnt,
                                                    int* __restrict__ ptr,
                                                    int* __restrict__ fill) {
    __shared__ int sums[1024];
    const int t = threadIdx.x;
    const int CHUNK = (NN + 1023) / 1024; // 49
    int lo = t * CHUNK;
    int hi = min(lo + CHUNK, NN);
    int s = 0;
    for (int i = lo; i < hi; ++i) s += cnt[i];
    sums[t] = s;
    __syncthreads();
    for (int off = 1; off < 1024; off <<= 1) {
        int v = (t >= off) ? sums[t - off] : 0;
        __syncthreads();
        sums[t] += v;
        __syncthreads();
    }
    int run = (t == 0) ? 0 : sums[t - 1];
    if (t == 1023) ptr[NN] = sums[1023]; // == NE
    for (int i = lo; i < hi; ++i) { ptr[i] = run; fill[i] = run; run += cnt[i]; }
}

// ---- CSR fill: bucket edges by target; precompute per-edge norm ------------
__global__ __launch_bounds__(256) void fill_kernel(const int* __restrict__ row,
                                                   const int* __restrict__ col,
                                                   const float* __restrict__ dis,
                                                   int* __restrict__ fill,
                                                   int* __restrict__ srow,
                                                   float* __restrict__ snorm) {
    int e = blockIdx.x * blockDim.x + threadIdx.x;
    if (e >= NE) return;
    int r = row[e], c = col[e];
    int p = atomicAdd(&fill[c], 1);
    srow[p] = r;
    snorm[p] = dis[r] * dis[c];
}

// ---- GEMM v3: one thread per output row, W via SGPR broadcast --------------
// xwb[n,b,:] (bf16, (N,B,D) layout) = x[b,n,:] @ W.  No LDS, no barriers.
// acc[64] in VGPRs; W[k][c] addresses are thread-uniform -> s_load broadcast.
__global__ __launch_bounds__(256) void gemm_kernel(const float* __restrict__ x,
                                                   const float* __restrict__ W,
                                                   unsigned short* __restrict__ xwb) {
    const long r = (long)blockIdx.x * blockDim.x + threadIdx.x;
    if (r >= (long)NB * NN) return;
    const float* xr = x + r * ND;

    float acc[64];
#pragma unroll
    for (int c = 0; c < 64; ++c) acc[c] = 0.0f;

#pragma unroll 1
    for (int k = 0; k < 64; k += 4) {
        float4 xv = *(const float4*)(xr + k);
        const float* w0 = W + (long)k * 64;
#pragma unroll
        for (int c = 0; c < 64; ++c) {
            acc[c] = fmaf(xv.x, w0[c], acc[c]);
            acc[c] = fmaf(xv.y, w0[64 + c], acc[c]);
            acc[c] = fmaf(xv.z, w0[128 + c], acc[c]);
            acc[c] = fmaf(xv.w, w0[192 + c], acc[c]);
        }
    }

    int b = (int)(r / NN);
    int n = (int)(r - (long)b * NN);
    unsigned short* dst = xwb + ((long)n * NB + b) * ND; // 128B contiguous per thread
#pragma unroll
    for (int c0 = 0; c0 < 64; c0 += 8) {
        uint4 p;
        p.x = (uint_t)f2b(acc[c0 + 0]) | ((uint_t)f2b(acc[c0 + 1]) << 16);
        p.y = (uint_t)f2b(acc[c0 + 2]) | ((uint_t)f2b(acc[c0 + 3]) << 16);
        p.z = (uint_t)f2b(acc[c0 + 4]) | ((uint_t)f2b(acc[c0 + 5]) << 16);
        p.w = (uint_t)f2b(acc[c0 + 6]) | ((uint_t)f2b(acc[c0 + 7]) << 16);
        *(uint4*)(dst + c0) = p;
    }
}

// ---- fused gather + self-loop + bias + tanh (bf16 xw, f32 accum) -----------
// One wave per target node. lane owns (b = lane>>4, d0 = (lane&15)*4).
__global__ __launch_bounds__(256) void gather_kernel(const int* __restrict__ ptr,
                                                     const int* __restrict__ srow,
                                                     const float* __restrict__ snorm,
                                                     const float* __restrict__ dis,
                                                     const unsigned short* __restrict__ xwb,
                                                     const float* __restrict__ bias,
                                                     float* __restrict__ out) {
    int node = blockIdx.x * 4 + (threadIdx.x >> 6);
    if (node >= NN) return;
    const int lane = threadIdx.x & 63;
    const int b = lane >> 4;
    const int d0 = (lane & 15) * 4;

    // self-loop: xw[node] * dis[node]^2
    float dn = dis[node];
    float sl = dn * dn;
    float4 acc = b2f4(*(const ushort4*)(xwb + (long)node * (NB * ND) + lane * 4));
    acc.x *= sl; acc.y *= sl; acc.z *= sl; acc.w *= sl;

    int e = ptr[node];
    const int eend = ptr[node + 1];
    for (; e + 3 < eend; e += 4) {
        int r0 = srow[e], r1 = srow[e + 1], r2 = srow[e + 2], r3 = srow[e + 3];
        float n0 = snorm[e], n1 = snorm[e + 1], n2 = snorm[e + 2], n3 = snorm[e + 3];
        float4 v0 = b2f4(*(const ushort4*)(xwb + (long)r0 * (NB * ND) + lane * 4));
        float4 v1 = b2f4(*(const ushort4*)(xwb + (long)r1 * (NB * ND) + lane * 4));
        float4 v2 = b2f4(*(const ushort4*)(xwb + (long)r2 * (NB * ND) + lane * 4));
        float4 v3 = b2f4(*(const ushort4*)(xwb + (long)r3 * (NB * ND) + lane * 4));
        acc.x = fmaf(v0.x, n0, acc.x); acc.y = fmaf(v0.y, n0, acc.y);
        acc.z = fmaf(v0.z, n0, acc.z); acc.w = fmaf(v0.w, n0, acc.w);
        acc.x = fmaf(v1.x, n1, acc.x); acc.y = fmaf(v1.y, n1, acc.y);
        acc.z = fmaf(v1.z, n1, acc.z); acc.w = fmaf(v1.w, n1, acc.w);
        acc.x = fmaf(v2.x, n2, acc.x); acc.y = fmaf(v2.y, n2, acc.y);
        acc.z = fmaf(v2.z, n2, acc.z); acc.w = fmaf(v2.w, n2, acc.w);
        acc.x = fmaf(v3.x, n3, acc.x); acc.y = fmaf(v3.y, n3, acc.y);
        acc.z = fmaf(v3.z, n3, acc.z); acc.w = fmaf(v3.w, n3, acc.w);
    }
    for (; e < eend; ++e) {
        int r0 = srow[e];
        float n0 = snorm[e];
        float4 v0 = b2f4(*(const ushort4*)(xwb + (long)r0 * (NB * ND) + lane * 4));
        acc.x = fmaf(v0.x, n0, acc.x); acc.y = fmaf(v0.y, n0, acc.y);
        acc.z = fmaf(v0.z, n0, acc.z); acc.w = fmaf(v0.w, n0, acc.w);
    }

    // bias + tanh, write f32 to (B,N,D)
    acc.x = tanhf(acc.x + bias[d0 + 0]);
    acc.y = tanhf(acc.y + bias[d0 + 1]);
    acc.z = tanhf(acc.z + bias[d0 + 2]);
    acc.w = tanhf(acc.w + bias[d0 + 3]);
    *(float4*)(out + (long)b * NN * ND + (long)node * ND + d0) = acc;
}

extern "C" void kernel_launch(void* const* d_in, const int* in_sizes, int n_in,
                              void* d_out, int out_size, void* d_ws, size_t ws_size,
                              hipStream_t stream) {
    // inputs: 0=t, 1=h, 2=edge_index, 3=W1, 4=b1, 5=W2, 6=b2
    const float* h  = (const float*)d_in[1];
    const int*   ei = (const int*)d_in[2];
    const float* W1 = (const float*)d_in[3];
    const float* b1 = (const float*)d_in[4];
    const float* W2 = (const float*)d_in[5];
    const float* b2 = (const float*)d_in[6];
    float* out = (float*)d_out;

    const int* rowp = ei;        // edge_index[0] = sources
    const int* colp = ei + NE;   // edge_index[1] = targets

    // workspace layout
    unsigned short* xwb = (unsigned short*)d_ws;   // TOT bf16 (N,B,D)
    float* dis  = (float*)d_ws + TOT / 2;          // NN floats
    float* snorm= dis + NN;                        // NE
    int*   cnt  = (int*)(snorm + NE);              // NN
    int*   ptr  = cnt + NN;                        // NN+1
    int*   fill = ptr + NN + 1;                    // NN
    int*   srow = fill + NN;                       // NE

    const int THREADS = 256;
    const int gridE = (NE + THREADS - 1) / THREADS;
    const int gridN = (NN + THREADS - 1) / THREADS;
    const int gridGemm   = (int)(((long)NB * NN + THREADS - 1) / THREADS); // 782
    const int gridGather = (NN + 3) / 4;

    // ---- normalization + CSR build ----
    hipMemsetAsync(cnt, 0, NN * sizeof(int), stream);
    count_kernel<<<gridE, THREADS, 0, stream>>>(colp, cnt);
    dis_kernel<<<gridN, THREADS, 0, stream>>>(cnt, dis);
    scan_kernel<<<1, 1024, 0, stream>>>(cnt, ptr, fill);
    fill_kernel<<<gridE, THREADS, 0, stream>>>(rowp, colp, dis, fill, srow, snorm);

    // ---- layer 1: h -> out ----
    gemm_kernel<<<gridGemm, THREADS, 0, stream>>>(h, W1, xwb);
    gather_kernel<<<gridGather, THREADS, 0, stream>>>(ptr, srow, snorm, dis, xwb, b1, out);

    // ---- layer 2: out -> out ----
    gemm_kernel<<<gridGemm, THREADS, 0, stream>>>(out, W2, xwb);
    gather_kernel<<<gridGather, THREADS, 0, stream>>>(ptr, srow, snorm, dis, xwb, b2, out);
}

// Round 5
// 381.946 us; speedup vs baseline: 4.9497x; 1.4660x over previous
//
#include <hip/hip_runtime.h>
#include <math.h>

// Problem constants (from reference): B=4, N=50000, E=800000, D=64
#define NB 4
#define NN 50000
#define NE 800000
#define ND 64
#define RTOT (NB * NN)            // 200000 rows
#define NBLK ((NN + 255) / 256)   // 196 scan blocks

static const long TOT = (long)NB * NN * ND; // 12,800,000 elements

typedef unsigned int uint_t;

// f32 -> bf16 (round-to-nearest-even)
__device__ __forceinline__ unsigned short f2b(float f) {
    unsigned x = __float_as_uint(f);
    unsigned r = (x + 0x7fffu + ((x >> 16) & 1u)) >> 16;
    return (unsigned short)r;
}
__device__ __forceinline__ float b2f(unsigned short u) {
    return __uint_as_float(((unsigned)u) << 16);
}
__device__ __forceinline__ float4 b2f4(ushort4 u) {
    float4 f;
    f.x = b2f(u.x); f.y = b2f(u.y); f.z = b2f(u.z); f.w = b2f(u.w);
    return f;
}

// ---- count in-degree (targets): cnt[col[e]] += 1 ---------------------------
__global__ __launch_bounds__(256) void count_kernel(const int* __restrict__ col,
                                                    int* __restrict__ cnt) {
    int e = blockIdx.x * blockDim.x + threadIdx.x;
    if (e < NE) atomicAdd(&cnt[col[e]], 1);
}

// ---- dis[n] = rsqrt(cnt[n] + 1)  (+1 = self-loop) --------------------------
__global__ __launch_bounds__(256) void dis_kernel(const int* __restrict__ cnt,
                                                  float* __restrict__ dis) {
    int n = blockIdx.x * blockDim.x + threadIdx.x;
    if (n < NN) dis[n] = rsqrtf((float)cnt[n] + 1.0f);
}

// ---- scan stage 1: per-256-chunk sums --------------------------------------
__global__ __launch_bounds__(256) void blocksum_kernel(const int* __restrict__ cnt,
                                                       int* __restrict__ bsum) {
    int i = blockIdx.x * 256 + threadIdx.x;
    int v = (i < NN) ? cnt[i] : 0;
#pragma unroll
    for (int off = 32; off; off >>= 1) v += __shfl_down(v, off);
    __shared__ int s[4];
    if ((threadIdx.x & 63) == 0) s[threadIdx.x >> 6] = v;
    __syncthreads();
    if (threadIdx.x == 0) bsum[blockIdx.x] = s[0] + s[1] + s[2] + s[3];
}

// ---- scan stage 2: exclusive scan of NBLK partials (1 block) ---------------
__global__ __launch_bounds__(256) void scanb_kernel(const int* __restrict__ bsum,
                                                    int* __restrict__ boff,
                                                    int* __restrict__ ptr) {
    __shared__ int s[256];
    int t = threadIdx.x;
    int v = (t < NBLK) ? bsum[t] : 0;
    s[t] = v;
    __syncthreads();
    for (int off = 1; off < 256; off <<= 1) {
        int u = (t >= off) ? s[t - off] : 0;
        __syncthreads();
        s[t] += u;
        __syncthreads();
    }
    boff[t] = s[t] - v; // exclusive
    if (t == 255) ptr[NN] = s[255]; // == NE
}

// ---- scan stage 3: emit ptr / fill -----------------------------------------
__global__ __launch_bounds__(256) void emit_kernel(const int* __restrict__ cnt,
                                                   const int* __restrict__ boff,
                                                   int* __restrict__ ptr,
                                                   int* __restrict__ fill) {
    __shared__ int s[256];
    int t = threadIdx.x;
    int i = blockIdx.x * 256 + t;
    int v = (i < NN) ? cnt[i] : 0;
    s[t] = v;
    __syncthreads();
    for (int off = 1; off < 256; off <<= 1) {
        int u = (t >= off) ? s[t - off] : 0;
        __syncthreads();
        s[t] += u;
        __syncthreads();
    }
    if (i < NN) {
        int ex = boff[blockIdx.x] + s[t] - v;
        ptr[i] = ex;
        fill[i] = ex;
    }
}

// ---- CSR fill: bucket edges by target; pack (src, norm) as int2 ------------
__global__ __launch_bounds__(256) void fill_kernel(const int* __restrict__ row,
                                                   const int* __restrict__ col,
                                                   const float* __restrict__ dis,
                                                   int* __restrict__ fill,
                                                   int2* __restrict__ sedge) {
    int e = blockIdx.x * blockDim.x + threadIdx.x;
    if (e >= NE) return;
    int r = row[e], c = col[e];
    int p = atomicAdd(&fill[c], 1);
    sedge[p] = make_int2(r, __float_as_int(dis[r] * dis[c]));
}

// ---- GEMM v4: 128-row tile, X staged bf16 (k-paired) + W f32 in LDS --------
// 256 threads, microtile 8 rows x 4 cols. Output xwb (N,B,D) bf16.
#define XS_STRIDE 33  // dwords per row: 32 k-pairs + 1 pad
__global__ __launch_bounds__(256) void gemm_kernel(const float* __restrict__ x,
                                                   const float* __restrict__ W,
                                                   unsigned short* __restrict__ xwb) {
    __shared__ unsigned XsU[128 * XS_STRIDE]; // [lr][k2] bf16 pairs, 16.9 KB
    __shared__ float Ws[4096];                // [k][c], 16 KB
    const int tid = threadIdx.x;
    const int row0 = blockIdx.x * 128;

    for (int i = tid; i < 4096; i += 256) Ws[i] = W[i];
#pragma unroll
    for (int j = 0; j < 8; ++j) {
        int c = tid + j * 256;          // 2048 float4-chunks
        int lr = c >> 4;                // 128 rows
        int k0 = (c & 15) * 4;          // 16 chunks/row
        int R = row0 + lr;
        float4 xv = (R < RTOT) ? *(const float4*)(x + (long)R * ND + k0)
                               : make_float4(0.f, 0.f, 0.f, 0.f);
        unsigned u0 = (uint_t)f2b(xv.x) | ((uint_t)f2b(xv.y) << 16);
        unsigned u1 = (uint_t)f2b(xv.z) | ((uint_t)f2b(xv.w) << 16);
        XsU[lr * XS_STRIDE + (k0 >> 1) + 0] = u0;
        XsU[lr * XS_STRIDE + (k0 >> 1) + 1] = u1;
    }
    __syncthreads();

    const int tc = tid & 15, tg = tid >> 4;
    const int c0 = tc * 4, r0 = tg * 8;
    float acc[8][4];
#pragma unroll
    for (int i = 0; i < 8; ++i)
#pragma unroll
        for (int j = 0; j < 4; ++j) acc[i][j] = 0.0f;

#pragma unroll 4
    for (int k2 = 0; k2 < 32; ++k2) {
        float4 w0 = *(const float4*)&Ws[(2 * k2) * 64 + c0];
        float4 w1 = *(const float4*)&Ws[(2 * k2 + 1) * 64 + c0];
#pragma unroll
        for (int i = 0; i < 8; ++i) {
            unsigned u = XsU[(r0 + i) * XS_STRIDE + k2];
            float xlo = __uint_as_float(u << 16);
            float xhi = __uint_as_float(u & 0xffff0000u);
            acc[i][0] = fmaf(xlo, w0.x, acc[i][0]);
            acc[i][1] = fmaf(xlo, w0.y, acc[i][1]);
            acc[i][2] = fmaf(xlo, w0.z, acc[i][2]);
            acc[i][3] = fmaf(xlo, w0.w, acc[i][3]);
            acc[i][0] = fmaf(xhi, w1.x, acc[i][0]);
            acc[i][1] = fmaf(xhi, w1.y, acc[i][1]);
            acc[i][2] = fmaf(xhi, w1.z, acc[i][2]);
            acc[i][3] = fmaf(xhi, w1.w, acc[i][3]);
        }
    }

#pragma unroll
    for (int i = 0; i < 8; ++i) {
        int R = row0 + r0 + i;
        if (R >= RTOT) break;
        int b = R / NN;
        int n = R - b * NN;
        ushort4 p;
        p.x = f2b(acc[i][0]); p.y = f2b(acc[i][1]);
        p.z = f2b(acc[i][2]); p.w = f2b(acc[i][3]);
        *(ushort4*)(xwb + ((long)n * NB + b) * ND + c0) = p;
    }
}

// ---- fused gather + self-loop + bias + tanh (scalar edge stream) -----------
// One wave per target node; node/edge data uniform -> SGPR + s_load.
__global__ __launch_bounds__(256) void gather_kernel(const int* __restrict__ ptr,
                                                     const int2* __restrict__ sedge,
                                                     const float* __restrict__ dis,
                                                     const unsigned short* __restrict__ xwb,
                                                     const float* __restrict__ bias,
                                                     float* __restrict__ out) {
    int node = __builtin_amdgcn_readfirstlane(blockIdx.x * 4 + (threadIdx.x >> 6));
    const int lane = threadIdx.x & 63;
    const int b = lane >> 4;
    const int d0 = (lane & 15) * 4;

    float dn = dis[node];
    float sl = dn * dn;
    float4 acc = b2f4(*(const ushort4*)(xwb + (long)node * (NB * ND) + lane * 4));
    acc.x *= sl; acc.y *= sl; acc.z *= sl; acc.w *= sl;

    int e = ptr[node];
    const int eend = ptr[node + 1];
    for (; e + 7 < eend; e += 8) {
        int2 E0 = sedge[e + 0], E1 = sedge[e + 1], E2 = sedge[e + 2], E3 = sedge[e + 3];
        int2 E4 = sedge[e + 4], E5 = sedge[e + 5], E6 = sedge[e + 6], E7 = sedge[e + 7];
        float4 v0 = b2f4(*(const ushort4*)(xwb + (long)E0.x * (NB * ND) + lane * 4));
        float4 v1 = b2f4(*(const ushort4*)(xwb + (long)E1.x * (NB * ND) + lane * 4));
        float4 v2 = b2f4(*(const ushort4*)(xwb + (long)E2.x * (NB * ND) + lane * 4));
        float4 v3 = b2f4(*(const ushort4*)(xwb + (long)E3.x * (NB * ND) + lane * 4));
        float4 v4 = b2f4(*(const ushort4*)(xwb + (long)E4.x * (NB * ND) + lane * 4));
        float4 v5 = b2f4(*(const ushort4*)(xwb + (long)E5.x * (NB * ND) + lane * 4));
        float4 v6 = b2f4(*(const ushort4*)(xwb + (long)E6.x * (NB * ND) + lane * 4));
        float4 v7 = b2f4(*(const ushort4*)(xwb + (long)E7.x * (NB * ND) + lane * 4));
        float n0 = __int_as_float(E0.y), n1 = __int_as_float(E1.y);
        float n2 = __int_as_float(E2.y), n3 = __int_as_float(E3.y);
        float n4 = __int_as_float(E4.y), n5 = __int_as_float(E5.y);
        float n6 = __int_as_float(E6.y), n7 = __int_as_float(E7.y);
        acc.x = fmaf(v0.x, n0, acc.x); acc.y = fmaf(v0.y, n0, acc.y);
        acc.z = fmaf(v0.z, n0, acc.z); acc.w = fmaf(v0.w, n0, acc.w);
        acc.x = fmaf(v1.x, n1, acc.x); acc.y = fmaf(v1.y, n1, acc.y);
        acc.z = fmaf(v1.z, n1, acc.z); acc.w = fmaf(v1.w, n1, acc.w);
        acc.x = fmaf(v2.x, n2, acc.x); acc.y = fmaf(v2.y, n2, acc.y);
        acc.z = fmaf(v2.z, n2, acc.z); acc.w = fmaf(v2.w, n2, acc.w);
        acc.x = fmaf(v3.x, n3, acc.x); acc.y = fmaf(v3.y, n3, acc.y);
        acc.z = fmaf(v3.z, n3, acc.z); acc.w = fmaf(v3.w, n3, acc.w);
        acc.x = fmaf(v4.x, n4, acc.x); acc.y = fmaf(v4.y, n4, acc.y);
        acc.z = fmaf(v4.z, n4, acc.z); acc.w = fmaf(v4.w, n4, acc.w);
        acc.x = fmaf(v5.x, n5, acc.x); acc.y = fmaf(v5.y, n5, acc.y);
        acc.z = fmaf(v5.z, n5, acc.z); acc.w = fmaf(v5.w, n5, acc.w);
        acc.x = fmaf(v6.x, n6, acc.x); acc.y = fmaf(v6.y, n6, acc.y);
        acc.z = fmaf(v6.z, n6, acc.z); acc.w = fmaf(v6.w, n6, acc.w);
        acc.x = fmaf(v7.x, n7, acc.x); acc.y = fmaf(v7.y, n7, acc.y);
        acc.z = fmaf(v7.z, n7, acc.z); acc.w = fmaf(v7.w, n7, acc.w);
    }
    for (; e < eend; ++e) {
        int2 E = sedge[e];
        float nv = __int_as_float(E.y);
        float4 v = b2f4(*(const ushort4*)(xwb + (long)E.x * (NB * ND) + lane * 4));
        acc.x = fmaf(v.x, nv, acc.x); acc.y = fmaf(v.y, nv, acc.y);
        acc.z = fmaf(v.z, nv, acc.z); acc.w = fmaf(v.w, nv, acc.w);
    }

    acc.x = tanhf(acc.x + bias[d0 + 0]);
    acc.y = tanhf(acc.y + bias[d0 + 1]);
    acc.z = tanhf(acc.z + bias[d0 + 2]);
    acc.w = tanhf(acc.w + bias[d0 + 3]);
    *(float4*)(out + (long)b * NN * ND + (long)node * ND + d0) = acc;
}

extern "C" void kernel_launch(void* const* d_in, const int* in_sizes, int n_in,
                              void* d_out, int out_size, void* d_ws, size_t ws_size,
                              hipStream_t stream) {
    // inputs: 0=t, 1=h, 2=edge_index, 3=W1, 4=b1, 5=W2, 6=b2
    const float* h  = (const float*)d_in[1];
    const int*   ei = (const int*)d_in[2];
    const float* W1 = (const float*)d_in[3];
    const float* b1 = (const float*)d_in[4];
    const float* W2 = (const float*)d_in[5];
    const float* b2 = (const float*)d_in[6];
    float* out = (float*)d_out;

    const int* rowp = ei;        // edge_index[0] = sources
    const int* colp = ei + NE;   // edge_index[1] = targets

    // workspace layout
    unsigned short* xwb = (unsigned short*)d_ws;      // TOT bf16 (N,B,D)
    int2*  sedge = (int2*)((char*)d_ws + TOT * 2);    // NE int2 (8B-aligned)
    float* dis   = (float*)(sedge + NE);              // NN
    int*   cnt   = (int*)(dis + NN);                  // NN
    int*   ptr   = cnt + NN;                          // NN+1
    int*   fill  = ptr + NN + 1;                      // NN
    int*   bsum  = fill + NN;                         // 256
    int*   boff  = bsum + 256;                        // 256

    const int THREADS = 256;
    const int gridE = (NE + THREADS - 1) / THREADS;
    const int gridN = (NN + THREADS - 1) / THREADS;
    const int gridGemm   = (RTOT + 127) / 128;  // 1563
    const int gridGather = NN / 4;              // 12500 (NN % 4 == 0)

    // ---- normalization + CSR build ----
    hipMemsetAsync(cnt, 0, NN * sizeof(int), stream);
    count_kernel<<<gridE, THREADS, 0, stream>>>(colp, cnt);
    dis_kernel<<<gridN, THREADS, 0, stream>>>(cnt, dis);
    blocksum_kernel<<<NBLK, THREADS, 0, stream>>>(cnt, bsum);
    scanb_kernel<<<1, THREADS, 0, stream>>>(bsum, boff, ptr);
    emit_kernel<<<NBLK, THREADS, 0, stream>>>(cnt, boff, ptr, fill);
    fill_kernel<<<gridE, THREADS, 0, stream>>>(rowp, colp, dis, fill, sedge);

    // ---- layer 1: h -> out ----
    gemm_kernel<<<gridGemm, THREADS, 0, stream>>>(h, W1, xwb);
    gather_kernel<<<gridGather, THREADS, 0, stream>>>(ptr, sedge, dis, xwb, b1, out);

    // ---- layer 2: out -> out ----
    gemm_kernel<<<gridGemm, THREADS, 0, stream>>>(out, W2, xwb);
    gather_kernel<<<gridGather, THREADS, 0, stream>>>(ptr, sedge, dis, xwb, b2, out);
}